// Round 12
// baseline (723.298 us; speedup 1.0000x reference)
//
#include <hip/hip_runtime.h>

#define NTOK 8192
#define TROWS 16384
#define DM 1024
#define HID 4096
#define NEXP 8
#define MAXT256 72
#define MAXT128 136

typedef __bf16 bf16x8 __attribute__((ext_vector_type(8)));
typedef float  f32x4  __attribute__((ext_vector_type(4)));
typedef short  s16x4  __attribute__((ext_vector_type(4)));
typedef short  s16x8  __attribute__((ext_vector_type(8)));

#define BAR() do { asm volatile("" ::: "memory"); __builtin_amdgcn_s_barrier(); asm volatile("" ::: "memory"); } while(0)
#define VM6() asm volatile("s_waitcnt vmcnt(6)" ::: "memory")
#define VM0() asm volatile("s_waitcnt vmcnt(0)" ::: "memory")

__device__ __forceinline__ short f2bf(float f) {
  union { float f; unsigned u; } v; v.f = f;
  unsigned r = (v.u + 0x7fffu + ((v.u >> 16) & 1u)) >> 16;  // RNE
  return (short)r;
}
__device__ __forceinline__ float bf2f(short s) {
  union { unsigned u; float f; } z; z.u = ((unsigned)(unsigned short)s) << 16; return z.f;
}

// async global->LDS, 16B/lane; LDS dest is wave-uniform base, lane i -> base + i*16
__device__ __forceinline__ void gload16(const short* g, short* l) {
  __builtin_amdgcn_global_load_lds(
      (const __attribute__((address_space(1))) void*)g,
      (__attribute__((address_space(3))) void*)l, 16, 0, 0);
}

// meta: [0:8) counts, [8:16) offs, [16:24) cursor,
// [32 + 3*s)  256-row tiles (expert,row0,rows)  s < 72   (gemm1)
// [256 + 3*s) 128-row tiles                      s < 136  (gemm2)

// parallel histogram: counts into meta[0:8) via global atomics (meta pre-zeroed)
__global__ void k_histo(const int* __restrict__ ei, int* __restrict__ meta) {
  int t = blockIdx.x * 256 + threadIdx.x;
  __shared__ int c[NEXP];
  if (threadIdx.x < NEXP) c[threadIdx.x] = 0;
  __syncthreads();
  atomicAdd(&c[ei[t]], 1);
  __syncthreads();
  if (threadIdx.x < NEXP) atomicAdd(&meta[threadIdx.x], c[threadIdx.x]);
}

// parallel planning: thread e (<8) writes expert e's offsets + tile entries;
// all 256 threads cooperatively zero-fill the table tails.
__global__ void k_plan(int* __restrict__ meta, float* __restrict__ outCounts) {
  int tid = threadIdx.x;
  int cnts[NEXP];
#pragma unroll
  for (int j = 0; j < NEXP; ++j) cnts[j] = meta[j];
  int tot256 = 0, tot128 = 0;
#pragma unroll
  for (int j = 0; j < NEXP; ++j) {
    tot256 += (cnts[j] + 255) >> 8;
    tot128 += (cnts[j] + 127) >> 7;
  }
  if (tid < NEXP) {
    int e = tid, off = 0, s = 0, s2 = 0;
    for (int j = 0; j < e; ++j) {
      off += cnts[j];
      s   += (cnts[j] + 255) >> 8;
      s2  += (cnts[j] + 127) >> 7;
    }
    int ce = cnts[e];
    meta[8 + e] = off;
    meta[16 + e] = off;
    outCounts[e] = (float)ce;        // output 1: tokens_per_expert
    for (int r0 = 0; r0 < ce; r0 += 256) {
      meta[32 + 3*s] = e; meta[32 + 3*s + 1] = off + r0;
      meta[32 + 3*s + 2] = (ce - r0 < 256) ? (ce - r0) : 256; ++s;
    }
    for (int r0 = 0; r0 < ce; r0 += 128) {
      meta[256 + 3*s2] = e; meta[256 + 3*s2 + 1] = off + r0;
      meta[256 + 3*s2 + 2] = (ce - r0 < 128) ? (ce - r0) : 128; ++s2;
    }
  }
  for (int s = tot256 + tid; s < MAXT256; s += 256) {
    meta[32 + 3*s] = 0; meta[32 + 3*s + 1] = 0; meta[32 + 3*s + 2] = 0;
  }
  for (int s2 = tot128 + tid; s2 < MAXT128; s2 += 256) {
    meta[256 + 3*s2] = 0; meta[256 + 3*s2 + 1] = 0; meta[256 + 3*s2 + 2] = 0;
  }
}

__global__ void k_scatter(const int* __restrict__ ei, int* __restrict__ meta,
                          int* __restrict__ rowmap, int* __restrict__ inv) {
  int t = blockIdx.x * blockDim.x + threadIdx.x;
  if (t < TROWS) {
    int e = ei[t];
    int p = atomicAdd(&meta[16 + e], 1);
    rowmap[p] = t;   // flat slot; token = t>>1, weight = ew[t]
    inv[t] = p;      // inverse: slot -> permuted row
  }
}

// ONE launch: 3 weight transposes (f32->bf16, (E,R,C)->(E,C,R)) + x conversion.
// Transpose via f32 LDS [64][65]: both phases are 2 lanes/bank = free (m136).
__global__ void k_prep(const float* __restrict__ w1, const float* __restrict__ w3,
                       const float* __restrict__ w2, const float* __restrict__ x,
                       short* __restrict__ w1t, short* __restrict__ w3t,
                       short* __restrict__ w2t, short* __restrict__ xb) {
  int b = blockIdx.x;                 // 0..32767
  int which = b >> 13;
  if (which == 3) {                   // cvt_x: 8192 blocks cover 2,097,152 f32x4 exactly
    int i = (b - 24576) * 256 + threadIdx.x;
    f32x4 v = ((const f32x4*)x)[i];
    s16x4 s = { f2bf(v.x), f2bf(v.y), f2bf(v.z), f2bf(v.w) };
    ((s16x4*)xb)[i] = s;
    return;
  }
  __shared__ float lt[64][65];
  int r = b & 8191;                   // 8192 blocks per matrix
  const float* in; short* out; int R, C;
  if (which == 0)      { in = w1; out = w1t; R = DM;  C = HID; }
  else if (which == 1) { in = w3; out = w3t; R = DM;  C = HID; }
  else                 { in = w2; out = w2t; R = HID; C = DM;  }
  int nx = C >> 6;
  int e = r >> 10;
  int rem = r & 1023;
  int c0 = (rem & (nx - 1)) * 64, r0 = (rem / nx) * 64;

  int t = threadIdx.x;
  int rr = t >> 4, cc = (t & 15) * 4;
  const float* src = in + ((size_t)e * R + r0 + rr) * C + c0 + cc;
#pragma unroll
  for (int i = 0; i < 4; ++i)
    *(f32x4*)&lt[rr + i*16][cc] = *(const f32x4*)(src + (size_t)i * 16 * C);
  __syncthreads();
  int cN = t >> 4, r4 = (t & 15) * 4;
  short* dst = out + ((size_t)e * C + c0 + cN) * R + r0 + r4;
#pragma unroll
  for (int i = 0; i < 4; ++i) {
    s16x4 o;
#pragma unroll
    for (int j = 0; j < 4; ++j) o[j] = f2bf(lt[r4 + j][cN + i*16]);
    *(s16x4*)(dst + (size_t)i * 16 * R) = o;
  }
}

// ---------------- GEMM1: 2-window / 4-barrier schedule ----------------
// h = silu(x@w1)*(x@w3). BM=256 BN=128 BK=64, 8 waves (2Mx4N), wave tile 128x32 dual.
// Window 1: read alo+b1w+b3w (16), stage Ah1(t+1); BAR; 32 MFMA (acc1lo,acc3lo);
//   stage B1(t+2); BAR.
// Window 2: read ahi (8), stage B3(t+2); BAR; 32 MFMA (acc1hi,acc3hi);
//   stage Ah0(t+2); VM6; BAR.  (halves barrier count vs R5; peak live frags
//   unchanged at 16 -> no VGPR growth; stage/ledger identical: 8 issues/tile, VM6->6)
__global__ __launch_bounds__(512, 2) void k_gemm1(
    const short* __restrict__ xb, const short* __restrict__ w1t, const short* __restrict__ w3t,
    const int* __restrict__ rowmap, const int* __restrict__ meta, short* __restrict__ hbuf) {
  int bid = blockIdx.x;                        // 2304 blocks = 8 XCD x 288
  int swz = (bid & 7) * 288 + (bid >> 3);
  int slot = swz % MAXT256;
  int bn   = swz / MAXT256;                    // 0..31 over HID/128
  int rows = meta[32 + 3*slot + 2];
  if (rows <= 0) return;
  int e    = meta[32 + 3*slot];
  int row0 = meta[32 + 3*slot + 1];

  __shared__ short lA [2][256 * 64];   // 64 KB
  __shared__ short lB1[2][128 * 64];   // 32 KB
  __shared__ short lB3[2][128 * 64];   // 32 KB

  int tid = threadIdx.x, l = tid & 63, w = tid >> 6;
  int wr = (w >> 2) * 128, wc = (w & 3) * 32;
  int lr = l & 15, cb = (l >> 4) * 16, axor = (lr & 7) << 4;
  int srow = l >> 3;
  int scol = ((l & 7) ^ srow) * 8;             // inverse-swizzled source col

  const short* aG[2][2];
#pragma unroll
  for (int h = 0; h < 2; ++h)
#pragma unroll
    for (int i = 0; i < 2; ++i) {
      int r = h*128 + w*16 + i*8 + srow;
      int rc = r < rows ? r : rows - 1;        // clamp ragged tail
      int tok = rowmap[row0 + rc] >> 1;
      aG[h][i] = xb + (size_t)tok * DM + scol;
    }
  const short *b1G[2], *b3G[2];
#pragma unroll
  for (int i = 0; i < 2; ++i) {
    size_t grow = (size_t)e * HID + (size_t)bn * 128 + w*16 + i*8 + srow;
    b1G[i] = w1t + grow * DM + scol;
    b3G[i] = w3t + grow * DM + scol;
  }

  f32x4 acc1[2][4][2], acc3[2][4][2];
#pragma unroll
  for (int h = 0; h < 2; ++h)
#pragma unroll
    for (int i = 0; i < 4; ++i)
#pragma unroll
      for (int j = 0; j < 2; ++j) {
        acc1[h][i][j] = (f32x4){0.f,0.f,0.f,0.f};
        acc3[h][i][j] = (f32x4){0.f,0.f,0.f,0.f};
      }

  auto stgA = [&](int buf, int h, int kt) {
    gload16(aG[h][0] + kt, &lA[buf][(h*128 + w*16    ) * 64]);
    gload16(aG[h][1] + kt, &lA[buf][(h*128 + w*16 + 8) * 64]);
  };
  auto stgB1 = [&](int buf, int kt) {
    gload16(b1G[0] + kt, &lB1[buf][(w*16    ) * 64]);
    gload16(b1G[1] + kt, &lB1[buf][(w*16 + 8) * 64]);
  };
  auto stgB3 = [&](int buf, int kt) {
    gload16(b3G[0] + kt, &lB3[buf][(w*16    ) * 64]);
    gload16(b3G[1] + kt, &lB3[buf][(w*16 + 8) * 64]);
  };

  // prologue: t0 full (4 halves), t1 partial (B1,B3,Ah0); t1.Ah1 comes at t0.W1
  stgA(0, 0, 0); stgA(0, 1, 0); stgB1(0, 0); stgB3(0, 0);
  stgB1(1, 64); stgB3(1, 64); stgA(1, 0, 64);
  VM6();                                       // t0 complete; t1's 3 halves in flight
  BAR();

  const int NT = DM / 64;                      // 16
  int c = 0;
  for (int t = 0; t < NT; ++t, c ^= 1) {
    int kn  = t*64 + 64;
    int kn2 = t*64 + 128;
    const char* cA  = (const char*)&lA [c][0];
    const char* cB1 = (const char*)&lB1[c][0];
    const char* cB3 = (const char*)&lB3[c][0];

    // ---- Window 1: read alo(8) + b1w(4) + b3w(4); stage t+1.Ah1 -> buf[c^1]
    bf16x8 alo[4][2], b1w[2][2], b3w[2][2];
#pragma unroll
    for (int i = 0; i < 4; ++i)
#pragma unroll
      for (int kk = 0; kk < 2; ++kk)
        alo[i][kk] = *(const bf16x8*)(cA + (wr + i*16 + lr)*128 + ((kk*64 + cb) ^ axor));
#pragma unroll
    for (int j = 0; j < 2; ++j)
#pragma unroll
      for (int kk = 0; kk < 2; ++kk) {
        b1w[j][kk] = *(const bf16x8*)(cB1 + (wc + j*16 + lr)*128 + ((kk*64 + cb) ^ axor));
        b3w[j][kk] = *(const bf16x8*)(cB3 + (wc + j*16 + lr)*128 + ((kk*64 + cb) ^ axor));
      }
    if (t + 1 < NT) stgA(c ^ 1, 1, kn);
    BAR();
    __builtin_amdgcn_s_setprio(1);
#pragma unroll
    for (int i = 0; i < 4; ++i)
#pragma unroll
      for (int j = 0; j < 2; ++j)
#pragma unroll
        for (int kk = 0; kk < 2; ++kk) {
          acc1[0][i][j] = __builtin_amdgcn_mfma_f32_16x16x32_bf16(alo[i][kk], b1w[j][kk], acc1[0][i][j], 0, 0, 0);
          acc3[0][i][j] = __builtin_amdgcn_mfma_f32_16x16x32_bf16(alo[i][kk], b3w[j][kk], acc3[0][i][j], 0, 0, 0);
        }
    __builtin_amdgcn_s_setprio(0);
    if (t + 2 < NT) stgB1(c, kn2);
    BAR();

    // ---- Window 2: read ahi(8); stage t+2.B3 -> buf[c]
    bf16x8 ahi[4][2];
#pragma unroll
    for (int i = 0; i < 4; ++i)
#pragma unroll
      for (int kk = 0; kk < 2; ++kk)
        ahi[i][kk] = *(const bf16x8*)(cA + (wr + 64 + i*16 + lr)*128 + ((kk*64 + cb) ^ axor));
    if (t + 2 < NT) stgB3(c, kn2);
    BAR();
    __builtin_amdgcn_s_setprio(1);
#pragma unroll
    for (int i = 0; i < 4; ++i)
#pragma unroll
      for (int j = 0; j < 2; ++j)
#pragma unroll
        for (int kk = 0; kk < 2; ++kk) {
          acc1[1][i][j] = __builtin_amdgcn_mfma_f32_16x16x32_bf16(ahi[i][kk], b1w[j][kk], acc1[1][i][j], 0, 0, 0);
          acc3[1][i][j] = __builtin_amdgcn_mfma_f32_16x16x32_bf16(ahi[i][kk], b3w[j][kk], acc3[1][i][j], 0, 0, 0);
        }
    __builtin_amdgcn_s_setprio(0);
    if (t + 2 < NT) stgA(c, 0, kn2);
    if (t < NT - 2) { VM6(); } else { VM0(); }
    BAR();
  }

  // epilogue: SwiGLU, bf16 store. C/D: col = lane&15, row = (lane>>4)*4 + q (m89)
#pragma unroll
  for (int h = 0; h < 2; ++h)
#pragma unroll
    for (int i = 0; i < 4; ++i)
#pragma unroll
      for (int q = 0; q < 4; ++q) {
        int r = wr + h*64 + i*16 + (l >> 4)*4 + q;
        if (r < rows) {
          size_t base = (size_t)(row0 + r) * HID + (size_t)bn * 128 + wc;
#pragma unroll
          for (int j = 0; j < 2; ++j) {
            float g = acc1[h][i][j][q], u3 = acc3[h][i][j][q];
            float sv = g / (1.f + __expf(-g));
            hbuf[base + j*16 + lr] = f2bf(sv * u3);
          }
        }
      }
}

// ---------------- GEMM2: m97-exact structure (proven R8) ----------------
// y[perm_row] = h @ w2 (bf16 out). BM=128 BN=128 BK=64, 4 waves, wave tile 64x64.
// SINGLE 32KB LDS buffer, plain __syncthreads; ~4 blocks/CU hides the drain.
// Slot-major XCD swizzle (proven R10): the 8 bn-blocks of a slot co-resident ->
// shared hb A-slab stays L2-hot.
__global__ __launch_bounds__(256) void k_gemm2(
    const short* __restrict__ hbuf, const short* __restrict__ w2t,
    const int* __restrict__ meta, short* __restrict__ y) {
  int bid = blockIdx.x;                       // 1088 blocks = 8 XCD x 136
  int xcd = bid & 7, rk = bid >> 3;           // rk in [0,136)
  int slot = xcd * 17 + (rk >> 3);
  int bn   = rk & 7;                          // 0..7 over DM/128
  int rows = meta[256 + 3*slot + 2];
  if (rows <= 0) return;
  int e    = meta[256 + 3*slot];
  int row0 = meta[256 + 3*slot + 1];

  __shared__ short lA[128 * 64];    // 16 KB
  __shared__ short lB[128 * 64];    // 16 KB

  int tid = threadIdx.x;
  int l = tid & 63, w = tid >> 6;

  int srow = w*8 + (l >> 3);
  int scol = ((l & 7) ^ (l >> 3)) * 8;        // inverse-swizzled source col

  const short* aG[4];
  for (int p = 0; p < 4; ++p) {
    int r = p*32 + srow;
    int rc = r < rows ? r : rows - 1;
    aG[p] = hbuf + (size_t)(row0 + rc) * HID + scol;
  }
  const short* bG[4];
  for (int p = 0; p < 4; ++p) {
    size_t grow = (size_t)e * DM + (size_t)bn * 128 + p*32 + srow;
    bG[p] = w2t + grow * HID + scol;
  }

  f32x4 acc[4][4];
  for (int i = 0; i < 4; ++i)
    for (int j = 0; j < 4; ++j) acc[i][j] = (f32x4){0.f, 0.f, 0.f, 0.f};

  int wr = (w >> 1) * 64, wc = (w & 1) * 64;
  int lr = l & 15;
  int cb = (l >> 4) * 16;
  int axor = (lr & 7) << 4;

  for (int kt = 0; kt < HID; kt += 64) {
#pragma unroll
    for (int p = 0; p < 4; ++p) {
      gload16(aG[p] + kt, &lA[(p*32 + w*8) * 64]);
      gload16(bG[p] + kt, &lB[(p*32 + w*8) * 64]);
    }
    __syncthreads();                 // compiler emits vmcnt(0) drain; occupancy hides it
#pragma unroll
    for (int kk2 = 0; kk2 < 2; ++kk2) {
      int co = (kk2*64 + cb) ^ axor;
      bf16x8 a[4], b[4];
#pragma unroll
      for (int i = 0; i < 4; ++i) a[i] = *(const bf16x8*)((const char*)lA + (wr + i*16 + lr)*128 + co);
#pragma unroll
      for (int j = 0; j < 4; ++j) b[j] = *(const bf16x8*)((const char*)lB + (wc + j*16 + lr)*128 + co);
#pragma unroll
      for (int i = 0; i < 4; ++i)
#pragma unroll
        for (int j = 0; j < 4; ++j)
          acc[i][j] = __builtin_amdgcn_mfma_f32_16x16x32_bf16(a[i], b[j], acc[i][j], 0, 0, 0);
    }
    __syncthreads();                 // protect LDS before next stage overwrites
  }

  for (int i = 0; i < 4; ++i)
    for (int q = 0; q < 4; ++q) {
      int r = wr + i*16 + (l >> 4)*4 + q;
      if (r < rows) {
        size_t obase = (size_t)(row0 + r) * DM + (size_t)bn * 128 + wc;
        for (int j = 0; j < 4; ++j)
          y[obase + j*16 + lr] = f2bf(acc[i][j][q]);
      }
    }
}

// out[tok] = ew[2t]*y[inv[2t]] + ew[2t+1]*y[inv[2t+1]]   (bf16 y, 8 elems/thread)
__global__ void k_unperm(const short* __restrict__ y, const int* __restrict__ inv,
                         const float* __restrict__ ew, float* __restrict__ out) {
  int i = blockIdx.x * 256 + threadIdx.x;      // 8-elem chunk id, DM/8=128 per token
  int tok = i >> 7, c = i & 127;
  int p0 = inv[2*tok], p1 = inv[2*tok + 1];
  float w0 = ew[2*tok], w1v = ew[2*tok + 1];
  s16x8 a = ((const s16x8*)y)[(size_t)p0 * 128 + c];
  s16x8 b = ((const s16x8*)y)[(size_t)p1 * 128 + c];
  f32x4 r0, r1;
#pragma unroll
  for (int j = 0; j < 4; ++j) r0[j] = w0 * bf2f(a[j])     + w1v * bf2f(b[j]);
#pragma unroll
  for (int j = 0; j < 4; ++j) r1[j] = w0 * bf2f(a[j + 4]) + w1v * bf2f(b[j + 4]);
  ((f32x4*)out)[2*i]     = r0;
  ((f32x4*)out)[2*i + 1] = r1;
}

extern "C" void kernel_launch(void* const* d_in, const int* in_sizes, int n_in,
                              void* d_out, int out_size, void* d_ws, size_t ws_size,
                              hipStream_t stream) {
  const float* x  = (const float*)d_in[0];
  const float* ew = (const float*)d_in[1];
  const int*   ei = (const int*)d_in[2];
  const float* w1 = (const float*)d_in[3];
  const float* w2 = (const float*)d_in[4];
  const float* w3 = (const float*)d_in[5];
  float* out = (float*)d_out;
  char*  ws  = (char*)d_ws;

  // workspace layout (bytes)
  short* w1t = (short*)(ws + 0);                    //  64 MB  (8,4096,1024) bf16
  short* w3t = (short*)(ws + 67108864);             //  64 MB
  short* w2t = (short*)(ws + 134217728);            //  64 MB  (8,1024,4096) bf16
  short* xb  = (short*)(ws + 201326592);            //  16 MB  (8192,1024) bf16
  short* hb  = (short*)(ws + 218103808);            // 128 MB  (16384,4096) bf16
  int*   meta   = (int*)(ws + 352321536);           //   8 KB
  int*   rowmap = (int*)(ws + 352321536 + 8192);    //  64 KB
  int*   inv    = (int*)(ws + 352321536 + 73728);   //  64 KB
  short* y      = (short*)(ws + 0);                 //  32 MB bf16, overlays w1t (dead after gemm1)

  hipMemsetAsync(meta, 0, NEXP * sizeof(int), stream);
  k_histo<<<TROWS / 256, 256, 0, stream>>>(ei, meta);
  k_plan<<<1, 256, 0, stream>>>(meta, out + (size_t)NTOK * DM);
  k_scatter<<<TROWS / 256, 256, 0, stream>>>(ei, meta, rowmap, inv);
  k_prep<<<32768, 256, 0, stream>>>(w1, w3, w2, x, w1t, w3t, w2t, xb);
  k_gemm1<<<MAXT256 * (HID/128), 512, 0, stream>>>(xb, w1t, w3t, rowmap, meta, hb);
  k_gemm2<<<MAXT128 * (DM/128), 256, 0, stream>>>(hb, w2t, meta, y);
  k_unperm<<<NTOK * DM / 8 / 256, 256, 0, stream>>>(y, inv, ew, out);
}

// Round 13
// 703.216 us; speedup vs baseline: 1.0286x; 1.0286x over previous
//
#include <hip/hip_runtime.h>

#define NTOK 8192
#define TROWS 16384
#define DM 1024
#define HID 4096
#define NEXP 8
#define MAXT256 72
#define MAXT128 136

typedef __bf16 bf16x8 __attribute__((ext_vector_type(8)));
typedef float  f32x4  __attribute__((ext_vector_type(4)));
typedef short  s16x4  __attribute__((ext_vector_type(4)));
typedef short  s16x8  __attribute__((ext_vector_type(8)));

#define BAR() do { asm volatile("" ::: "memory"); __builtin_amdgcn_s_barrier(); asm volatile("" ::: "memory"); } while(0)
#define VM6() asm volatile("s_waitcnt vmcnt(6)" ::: "memory")
#define VM0() asm volatile("s_waitcnt vmcnt(0)" ::: "memory")

__device__ __forceinline__ short f2bf(float f) {
  union { float f; unsigned u; } v; v.f = f;
  unsigned r = (v.u + 0x7fffu + ((v.u >> 16) & 1u)) >> 16;  // RNE
  return (short)r;
}
__device__ __forceinline__ float bf2f(short s) {
  union { unsigned u; float f; } z; z.u = ((unsigned)(unsigned short)s) << 16; return z.f;
}

// async global->LDS, 16B/lane; LDS dest is wave-uniform base, lane i -> base + i*16
__device__ __forceinline__ void gload16(const short* g, short* l) {
  __builtin_amdgcn_global_load_lds(
      (const __attribute__((address_space(1))) void*)g,
      (__attribute__((address_space(3))) void*)l, 16, 0, 0);
}

// meta: [0:8) counts, [8:16) offs, [16:24) cursor,
// [32 + 3*s)  256-row tiles (expert,row0,rows)  s < 72   (gemm1)
// [256 + 3*s) 128-row tiles                      s < 136  (gemm2)

// parallel histogram: counts into meta[0:8) via global atomics (meta pre-zeroed)
__global__ void k_histo(const int* __restrict__ ei, int* __restrict__ meta) {
  int t = blockIdx.x * 256 + threadIdx.x;
  __shared__ int c[NEXP];
  if (threadIdx.x < NEXP) c[threadIdx.x] = 0;
  __syncthreads();
  atomicAdd(&c[ei[t]], 1);
  __syncthreads();
  if (threadIdx.x < NEXP) atomicAdd(&meta[threadIdx.x], c[threadIdx.x]);
}

// parallel planning: thread e (<8) writes expert e's offsets + tile entries;
// all 256 threads cooperatively zero-fill the table tails.
__global__ void k_plan(int* __restrict__ meta, float* __restrict__ outCounts) {
  int tid = threadIdx.x;
  int cnts[NEXP];
#pragma unroll
  for (int j = 0; j < NEXP; ++j) cnts[j] = meta[j];
  int tot256 = 0, tot128 = 0;
#pragma unroll
  for (int j = 0; j < NEXP; ++j) {
    tot256 += (cnts[j] + 255) >> 8;
    tot128 += (cnts[j] + 127) >> 7;
  }
  if (tid < NEXP) {
    int e = tid, off = 0, s = 0, s2 = 0;
    for (int j = 0; j < e; ++j) {
      off += cnts[j];
      s   += (cnts[j] + 255) >> 8;
      s2  += (cnts[j] + 127) >> 7;
    }
    int ce = cnts[e];
    meta[8 + e] = off;
    meta[16 + e] = off;
    outCounts[e] = (float)ce;        // output 1: tokens_per_expert
    for (int r0 = 0; r0 < ce; r0 += 256) {
      meta[32 + 3*s] = e; meta[32 + 3*s + 1] = off + r0;
      meta[32 + 3*s + 2] = (ce - r0 < 256) ? (ce - r0) : 256; ++s;
    }
    for (int r0 = 0; r0 < ce; r0 += 128) {
      meta[256 + 3*s2] = e; meta[256 + 3*s2 + 1] = off + r0;
      meta[256 + 3*s2 + 2] = (ce - r0 < 128) ? (ce - r0) : 128; ++s2;
    }
  }
  for (int s = tot256 + tid; s < MAXT256; s += 256) {
    meta[32 + 3*s] = 0; meta[32 + 3*s + 1] = 0; meta[32 + 3*s + 2] = 0;
  }
  for (int s2 = tot128 + tid; s2 < MAXT128; s2 += 256) {
    meta[256 + 3*s2] = 0; meta[256 + 3*s2 + 1] = 0; meta[256 + 3*s2 + 2] = 0;
  }
}

__global__ void k_scatter(const int* __restrict__ ei, int* __restrict__ meta,
                          int* __restrict__ rowmap, int* __restrict__ inv) {
  int t = blockIdx.x * blockDim.x + threadIdx.x;
  if (t < TROWS) {
    int e = ei[t];
    int p = atomicAdd(&meta[16 + e], 1);
    rowmap[p] = t;   // flat slot; token = t>>1, weight = ew[t]
    inv[t] = p;      // inverse: slot -> permuted row
  }
}

// ONE launch: 3 weight transposes (f32->bf16, (E,R,C)->(E,C,R)) + x conversion.
// Transpose via f32 LDS [64][65]: both phases are 2 lanes/bank = free (m136).
__global__ void k_prep(const float* __restrict__ w1, const float* __restrict__ w3,
                       const float* __restrict__ w2, const float* __restrict__ x,
                       short* __restrict__ w1t, short* __restrict__ w3t,
                       short* __restrict__ w2t, short* __restrict__ xb) {
  int b = blockIdx.x;                 // 0..32767
  int which = b >> 13;
  if (which == 3) {                   // cvt_x: 8192 blocks cover 2,097,152 f32x4 exactly
    int i = (b - 24576) * 256 + threadIdx.x;
    f32x4 v = ((const f32x4*)x)[i];
    s16x4 s = { f2bf(v.x), f2bf(v.y), f2bf(v.z), f2bf(v.w) };
    ((s16x4*)xb)[i] = s;
    return;
  }
  __shared__ float lt[64][65];
  int r = b & 8191;                   // 8192 blocks per matrix
  const float* in; short* out; int R, C;
  if (which == 0)      { in = w1; out = w1t; R = DM;  C = HID; }
  else if (which == 1) { in = w3; out = w3t; R = DM;  C = HID; }
  else                 { in = w2; out = w2t; R = HID; C = DM;  }
  int nx = C >> 6;
  int e = r >> 10;
  int rem = r & 1023;
  int c0 = (rem & (nx - 1)) * 64, r0 = (rem / nx) * 64;

  int t = threadIdx.x;
  int rr = t >> 4, cc = (t & 15) * 4;
  const float* src = in + ((size_t)e * R + r0 + rr) * C + c0 + cc;
#pragma unroll
  for (int i = 0; i < 4; ++i)
    *(f32x4*)&lt[rr + i*16][cc] = *(const f32x4*)(src + (size_t)i * 16 * C);
  __syncthreads();
  int cN = t >> 4, r4 = (t & 15) * 4;
  short* dst = out + ((size_t)e * C + c0 + cN) * R + r0 + r4;
#pragma unroll
  for (int i = 0; i < 4; ++i) {
    s16x4 o;
#pragma unroll
    for (int j = 0; j < 4; ++j) o[j] = f2bf(lt[r4 + j][cN + i*16]);
    *(s16x4*)(dst + (size_t)i * 16 * R) = o;
  }
}

// ---------------- GEMM1: 8-phase schedule (proven R5/R11; R12's 2-window merge
// regressed -8% -> fine 4-phase interleave is load-bearing, per m196) ----------------
// h = silu(x@w1)*(x@w3). BM=256 BN=128 BK=64, 8 waves (2Mx4N), wave tile 128x32 dual.
__global__ __launch_bounds__(512, 2) void k_gemm1(
    const short* __restrict__ xb, const short* __restrict__ w1t, const short* __restrict__ w3t,
    const int* __restrict__ rowmap, const int* __restrict__ meta, short* __restrict__ hbuf) {
  int bid = blockIdx.x;                        // 2304 blocks = 8 XCD x 288
  int swz = (bid & 7) * 288 + (bid >> 3);
  int slot = swz % MAXT256;
  int bn   = swz / MAXT256;                    // 0..31 over HID/128
  int rows = meta[32 + 3*slot + 2];
  if (rows <= 0) return;
  int e    = meta[32 + 3*slot];
  int row0 = meta[32 + 3*slot + 1];

  __shared__ short lA [2][256 * 64];   // 64 KB
  __shared__ short lB1[2][128 * 64];   // 32 KB
  __shared__ short lB3[2][128 * 64];   // 32 KB

  int tid = threadIdx.x, l = tid & 63, w = tid >> 6;
  int wr = (w >> 2) * 128, wc = (w & 3) * 32;
  int lr = l & 15, cb = (l >> 4) * 16, axor = (lr & 7) << 4;
  int srow = l >> 3;
  int scol = ((l & 7) ^ srow) * 8;             // inverse-swizzled source col

  const short* aG[2][2];
#pragma unroll
  for (int h = 0; h < 2; ++h)
#pragma unroll
    for (int i = 0; i < 2; ++i) {
      int r = h*128 + w*16 + i*8 + srow;
      int rc = r < rows ? r : rows - 1;        // clamp ragged tail
      int tok = rowmap[row0 + rc] >> 1;
      aG[h][i] = xb + (size_t)tok * DM + scol;
    }
  const short *b1G[2], *b3G[2];
#pragma unroll
  for (int i = 0; i < 2; ++i) {
    size_t grow = (size_t)e * HID + (size_t)bn * 128 + w*16 + i*8 + srow;
    b1G[i] = w1t + grow * DM + scol;
    b3G[i] = w3t + grow * DM + scol;
  }

  f32x4 acc1[2][4][2], acc3[2][4][2];
#pragma unroll
  for (int h = 0; h < 2; ++h)
#pragma unroll
    for (int i = 0; i < 4; ++i)
#pragma unroll
      for (int j = 0; j < 2; ++j) {
        acc1[h][i][j] = (f32x4){0.f,0.f,0.f,0.f};
        acc3[h][i][j] = (f32x4){0.f,0.f,0.f,0.f};
      }

  auto stgA = [&](int buf, int h, int kt) {
    gload16(aG[h][0] + kt, &lA[buf][(h*128 + w*16    ) * 64]);
    gload16(aG[h][1] + kt, &lA[buf][(h*128 + w*16 + 8) * 64]);
  };
  auto stgB1 = [&](int buf, int kt) {
    gload16(b1G[0] + kt, &lB1[buf][(w*16    ) * 64]);
    gload16(b1G[1] + kt, &lB1[buf][(w*16 + 8) * 64]);
  };
  auto stgB3 = [&](int buf, int kt) {
    gload16(b3G[0] + kt, &lB3[buf][(w*16    ) * 64]);
    gload16(b3G[1] + kt, &lB3[buf][(w*16 + 8) * 64]);
  };

  // prologue: t0 full (4 halves), t1 partial (B1,B3,Ah0); t1.Ah1 comes at t0.P0
  stgA(0, 0, 0); stgA(0, 1, 0); stgB1(0, 0); stgB3(0, 0);
  stgB1(1, 64); stgB3(1, 64); stgA(1, 0, 64);
  VM6();                                       // t0 complete; t1's 3 halves in flight
  BAR();

  const int NT = DM / 64;                      // 16
  int c = 0;
  for (int t = 0; t < NT; ++t, c ^= 1) {
    int kn  = t*64 + 64;
    int kn2 = t*64 + 128;
    const char* cA  = (const char*)&lA [c][0];
    const char* cB1 = (const char*)&lB1[c][0];
    const char* cB3 = (const char*)&lB3[c][0];

    // ---- P0: read A-lo + B1w (12); stage t+1.Ah1 -> buf[c^1]
    bf16x8 alo[4][2], b1w[2][2];
#pragma unroll
    for (int i = 0; i < 4; ++i)
#pragma unroll
      for (int kk = 0; kk < 2; ++kk)
        alo[i][kk] = *(const bf16x8*)(cA + (wr + i*16 + lr)*128 + ((kk*64 + cb) ^ axor));
#pragma unroll
    for (int j = 0; j < 2; ++j)
#pragma unroll
      for (int kk = 0; kk < 2; ++kk)
        b1w[j][kk] = *(const bf16x8*)(cB1 + (wc + j*16 + lr)*128 + ((kk*64 + cb) ^ axor));
    if (t + 1 < NT) stgA(c ^ 1, 1, kn);
    BAR();
    __builtin_amdgcn_s_setprio(1);
#pragma unroll
    for (int i = 0; i < 4; ++i)
#pragma unroll
      for (int j = 0; j < 2; ++j)
#pragma unroll
        for (int kk = 0; kk < 2; ++kk)
          acc1[0][i][j] = __builtin_amdgcn_mfma_f32_16x16x32_bf16(alo[i][kk], b1w[j][kk], acc1[0][i][j], 0, 0, 0);
    __builtin_amdgcn_s_setprio(0);
    BAR();

    // ---- P1: read B3w (4); stage t+2.B1 -> buf[c]
    bf16x8 b3w[2][2];
#pragma unroll
    for (int j = 0; j < 2; ++j)
#pragma unroll
      for (int kk = 0; kk < 2; ++kk)
        b3w[j][kk] = *(const bf16x8*)(cB3 + (wc + j*16 + lr)*128 + ((kk*64 + cb) ^ axor));
    if (t + 2 < NT) stgB1(c, kn2);
    BAR();
    __builtin_amdgcn_s_setprio(1);
#pragma unroll
    for (int i = 0; i < 4; ++i)
#pragma unroll
      for (int j = 0; j < 2; ++j)
#pragma unroll
        for (int kk = 0; kk < 2; ++kk)
          acc3[0][i][j] = __builtin_amdgcn_mfma_f32_16x16x32_bf16(alo[i][kk], b3w[j][kk], acc3[0][i][j], 0, 0, 0);
    __builtin_amdgcn_s_setprio(0);
    BAR();

    // ---- P2: read A-hi (8); stage t+2.B3 -> buf[c]
    bf16x8 ahi[4][2];
#pragma unroll
    for (int i = 0; i < 4; ++i)
#pragma unroll
      for (int kk = 0; kk < 2; ++kk)
        ahi[i][kk] = *(const bf16x8*)(cA + (wr + 64 + i*16 + lr)*128 + ((kk*64 + cb) ^ axor));
    if (t + 2 < NT) stgB3(c, kn2);
    BAR();
    __builtin_amdgcn_s_setprio(1);
#pragma unroll
    for (int i = 0; i < 4; ++i)
#pragma unroll
      for (int j = 0; j < 2; ++j)
#pragma unroll
        for (int kk = 0; kk < 2; ++kk)
          acc1[1][i][j] = __builtin_amdgcn_mfma_f32_16x16x32_bf16(ahi[i][kk], b1w[j][kk], acc1[1][i][j], 0, 0, 0);
    __builtin_amdgcn_s_setprio(0);
    BAR();

    // ---- P3: stage t+2.Ah0 -> buf[c]; MFMA; counted vmcnt
    if (t + 2 < NT) stgA(c, 0, kn2);
    __builtin_amdgcn_s_setprio(1);
#pragma unroll
    for (int i = 0; i < 4; ++i)
#pragma unroll
      for (int j = 0; j < 2; ++j)
#pragma unroll
        for (int kk = 0; kk < 2; ++kk)
          acc3[1][i][j] = __builtin_amdgcn_mfma_f32_16x16x32_bf16(ahi[i][kk], b3w[j][kk], acc3[1][i][j], 0, 0, 0);
    __builtin_amdgcn_s_setprio(0);
    if (t < NT - 2) { VM6(); } else { VM0(); }
    BAR();
  }

  // epilogue: SwiGLU, bf16 store. C/D: col = lane&15, row = (lane>>4)*4 + q (m89)
#pragma unroll
  for (int h = 0; h < 2; ++h)
#pragma unroll
    for (int i = 0; i < 4; ++i)
#pragma unroll
      for (int q = 0; q < 4; ++q) {
        int r = wr + h*64 + i*16 + (l >> 4)*4 + q;
        if (r < rows) {
          size_t base = (size_t)(row0 + r) * HID + (size_t)bn * 128 + wc;
#pragma unroll
          for (int j = 0; j < 2; ++j) {
            float g = acc1[h][i][j][q], u3 = acc3[h][i][j][q];
            float sv = g / (1.f + __expf(-g));
            hbuf[base + j*16 + lr] = f2bf(sv * u3);
          }
        }
      }
}

// ---------------- GEMM2: m97-exact structure (proven R8) ----------------
// y[perm_row] = h @ w2 (bf16 out). BM=128 BN=128 BK=64, 4 waves, wave tile 64x64.
// SINGLE 32KB LDS buffer, plain __syncthreads; ~4 blocks/CU hides the drain.
// Slot-major XCD swizzle (proven R10): the 8 bn-blocks of a slot co-resident ->
// shared hb A-slab stays L2-hot.
__global__ __launch_bounds__(256) void k_gemm2(
    const short* __restrict__ hbuf, const short* __restrict__ w2t,
    const int* __restrict__ meta, short* __restrict__ y) {
  int bid = blockIdx.x;                       // 1088 blocks = 8 XCD x 136
  int xcd = bid & 7, rk = bid >> 3;           // rk in [0,136)
  int slot = xcd * 17 + (rk >> 3);
  int bn   = rk & 7;                          // 0..7 over DM/128
  int rows = meta[256 + 3*slot + 2];
  if (rows <= 0) return;
  int e    = meta[256 + 3*slot];
  int row0 = meta[256 + 3*slot + 1];

  __shared__ short lA[128 * 64];    // 16 KB
  __shared__ short lB[128 * 64];    // 16 KB

  int tid = threadIdx.x;
  int l = tid & 63, w = tid >> 6;

  int srow = w*8 + (l >> 3);
  int scol = ((l & 7) ^ (l >> 3)) * 8;        // inverse-swizzled source col

  const short* aG[4];
  for (int p = 0; p < 4; ++p) {
    int r = p*32 + srow;
    int rc = r < rows ? r : rows - 1;
    aG[p] = hbuf + (size_t)(row0 + rc) * HID + scol;
  }
  const short* bG[4];
  for (int p = 0; p < 4; ++p) {
    size_t grow = (size_t)e * DM + (size_t)bn * 128 + p*32 + srow;
    bG[p] = w2t + grow * HID + scol;
  }

  f32x4 acc[4][4];
  for (int i = 0; i < 4; ++i)
    for (int j = 0; j < 4; ++j) acc[i][j] = (f32x4){0.f, 0.f, 0.f, 0.f};

  int wr = (w >> 1) * 64, wc = (w & 1) * 64;
  int lr = l & 15;
  int cb = (l >> 4) * 16;
  int axor = (lr & 7) << 4;

  for (int kt = 0; kt < HID; kt += 64) {
#pragma unroll
    for (int p = 0; p < 4; ++p) {
      gload16(aG[p] + kt, &lA[(p*32 + w*8) * 64]);
      gload16(bG[p] + kt, &lB[(p*32 + w*8) * 64]);
    }
    __syncthreads();                 // compiler emits vmcnt(0) drain; occupancy hides it
#pragma unroll
    for (int kk2 = 0; kk2 < 2; ++kk2) {
      int co = (kk2*64 + cb) ^ axor;
      bf16x8 a[4], b[4];
#pragma unroll
      for (int i = 0; i < 4; ++i) a[i] = *(const bf16x8*)((const char*)lA + (wr + i*16 + lr)*128 + co);
#pragma unroll
      for (int j = 0; j < 4; ++j) b[j] = *(const bf16x8*)((const char*)lB + (wc + j*16 + lr)*128 + co);
#pragma unroll
      for (int i = 0; i < 4; ++i)
#pragma unroll
        for (int j = 0; j < 4; ++j)
          acc[i][j] = __builtin_amdgcn_mfma_f32_16x16x32_bf16(a[i], b[j], acc[i][j], 0, 0, 0);
    }
    __syncthreads();                 // protect LDS before next stage overwrites
  }

  for (int i = 0; i < 4; ++i)
    for (int q = 0; q < 4; ++q) {
      int r = wr + i*16 + (l >> 4)*4 + q;
      if (r < rows) {
        size_t obase = (size_t)(row0 + r) * DM + (size_t)bn * 128 + wc;
        for (int j = 0; j < 4; ++j)
          y[obase + j*16 + lr] = f2bf(acc[i][j][q]);
      }
    }
}

// out[tok] = ew[2t]*y[inv[2t]] + ew[2t+1]*y[inv[2t+1]]   (bf16 y, 8 elems/thread)
__global__ void k_unperm(const short* __restrict__ y, const int* __restrict__ inv,
                         const float* __restrict__ ew, float* __restrict__ out) {
  int i = blockIdx.x * 256 + threadIdx.x;      // 8-elem chunk id, DM/8=128 per token
  int tok = i >> 7, c = i & 127;
  int p0 = inv[2*tok], p1 = inv[2*tok + 1];
  float w0 = ew[2*tok], w1v = ew[2*tok + 1];
  s16x8 a = ((const s16x8*)y)[(size_t)p0 * 128 + c];
  s16x8 b = ((const s16x8*)y)[(size_t)p1 * 128 + c];
  f32x4 r0, r1;
#pragma unroll
  for (int j = 0; j < 4; ++j) r0[j] = w0 * bf2f(a[j])     + w1v * bf2f(b[j]);
#pragma unroll
  for (int j = 0; j < 4; ++j) r1[j] = w0 * bf2f(a[j + 4]) + w1v * bf2f(b[j + 4]);
  ((f32x4*)out)[2*i]     = r0;
  ((f32x4*)out)[2*i + 1] = r1;
}

extern "C" void kernel_launch(void* const* d_in, const int* in_sizes, int n_in,
                              void* d_out, int out_size, void* d_ws, size_t ws_size,
                              hipStream_t stream) {
  const float* x  = (const float*)d_in[0];
  const float* ew = (const float*)d_in[1];
  const int*   ei = (const int*)d_in[2];
  const float* w1 = (const float*)d_in[3];
  const float* w2 = (const float*)d_in[4];
  const float* w3 = (const float*)d_in[5];
  float* out = (float*)d_out;
  char*  ws  = (char*)d_ws;

  // workspace layout (bytes)
  short* w1t = (short*)(ws + 0);                    //  64 MB  (8,4096,1024) bf16
  short* w3t = (short*)(ws + 67108864);             //  64 MB
  short* w2t = (short*)(ws + 134217728);            //  64 MB  (8,1024,4096) bf16
  short* xb  = (short*)(ws + 201326592);            //  16 MB  (8192,1024) bf16
  short* hb  = (short*)(ws + 218103808);            // 128 MB  (16384,4096) bf16
  int*   meta   = (int*)(ws + 352321536);           //   8 KB
  int*   rowmap = (int*)(ws + 352321536 + 8192);    //  64 KB
  int*   inv    = (int*)(ws + 352321536 + 73728);   //  64 KB
  short* y      = (short*)(ws + 0);                 //  32 MB bf16, overlays w1t (dead after gemm1)

  hipMemsetAsync(meta, 0, NEXP * sizeof(int), stream);
  k_histo<<<TROWS / 256, 256, 0, stream>>>(ei, meta);
  k_plan<<<1, 256, 0, stream>>>(meta, out + (size_t)NTOK * DM);
  k_scatter<<<TROWS / 256, 256, 0, stream>>>(ei, meta, rowmap, inv);
  k_prep<<<32768, 256, 0, stream>>>(w1, w3, w2, x, w1t, w3t, w2t, xb);
  k_gemm1<<<MAXT256 * (HID/128), 512, 0, stream>>>(xb, w1t, w3t, rowmap, meta, hb);
  k_gemm2<<<MAXT128 * (DM/128), 256, 0, stream>>>(hb, w2t, meta, y);
  k_unperm<<<NTOK * DM / 8 / 256, 256, 0, stream>>>(y, inv, ew, out);
}